// Round 5
// baseline (491.692 us; speedup 1.0000x reference)
//
#include <hip/hip_runtime.h>
#include <hip/hip_bf16.h>
#include <stdint.h>

#define EMBED 256
#define HEADS 8
#define LEVELS 4
#define POINTS 4
#define HEAD_DIM 32
#define HPAD 128
#define WPAD 128
#define LN_EPS 1e-5f

typedef unsigned short u16;
typedef __attribute__((ext_vector_type(8))) short bf16x8v;
typedef __attribute__((ext_vector_type(4))) float f32x4;

static __device__ __forceinline__ float bu2f(u16 u) {
  return __uint_as_float(((unsigned)u) << 16);
}
static __device__ __forceinline__ u16 f2bu(float f) {   // fp32 -> bf16 RNE
  unsigned x = __float_as_uint(f);
  return (u16)((x + 0x7fffu + ((x >> 16) & 1u)) >> 16);
}
static __device__ __forceinline__ float loadf(const void* p, size_t i, int isbf) {
  return isbf ? bu2f(((const u16*)p)[i]) : ((const float*)p)[i];
}
static __device__ __forceinline__ int imin(int a, int b) { return a < b ? a : b; }

static __device__ __forceinline__ void cp16(const u16* g, u16* l) {
  __builtin_amdgcn_global_load_lds((const __attribute__((address_space(1))) unsigned*)g,
                                   (__attribute__((address_space(3))) unsigned*)l, 16, 0, 0);
}

// ------------- dtype probe -------------
__global__ __launch_bounds__(256) void detect_kernel(const unsigned* __restrict__ q,
                                                     int* __restrict__ flag) {
  int t = threadIdx.x;
  __shared__ int s[256];
  unsigned u = q[t * 13 + 1];
  unsigned e = (u >> 7) & 0xFF;
  s[t] = (e >= 116 && e <= 130) ? 1 : 0;
  __syncthreads();
  for (int st = 128; st > 0; st >>= 1) { if (t < st) s[t] += s[t + st]; __syncthreads(); }
  if (t == 0) *flag = (s[0] > 200) ? 1 : 0;   // 1 => bf16 elements
}

// ------------- combined off/attn bias (fp32) -------------
__global__ __launch_bounds__(384) void boa_kernel(const void* __restrict__ b_off,
                                                  const void* __restrict__ b_attn,
                                                  float* __restrict__ boa,
                                                  const int* __restrict__ dflag) {
  int fl = *dflag;
  int t = threadIdx.x;
  boa[t] = (t < 256) ? loadf(b_off, t, fl) : loadf(b_attn, t - 256, fl);
}

// ------------- coalesced tiled transpose: Wt[n*K+k] = bf16(W[k*N+n]) -------------
__global__ __launch_bounds__(256) void wtrans_kernel(const void* __restrict__ W,
                                                     u16* __restrict__ Wt,
                                                     int K, int N,
                                                     const int* __restrict__ dflag) {
  int fl = *dflag;
  __shared__ float tile[32][33];
  int tx = threadIdx.x & 31, ty = threadIdx.x >> 5;
  int k0 = blockIdx.x * 32, n0 = blockIdx.y * 32;
#pragma unroll
  for (int j = 0; j < 4; j++) {
    int r = ty + j * 8;
    tile[r][tx] = loadf(W, (size_t)(k0 + r) * N + n0 + tx, fl);
  }
  __syncthreads();
#pragma unroll
  for (int j = 0; j < 4; j++) {
    int n = ty + j * 8;
    Wt[(size_t)(n0 + n) * K + k0 + tx] = f2bu(tile[tx][n]);
  }
}

// ---------------- LayerNorm ----------------
__global__ __launch_bounds__(256) void ln_kernel(const void* __restrict__ q,
                                                 const void* __restrict__ g,
                                                 const void* __restrict__ be,
                                                 u16* __restrict__ out,
                                                 const int* __restrict__ dflag) {
  int fl = *dflag;
  int row = blockIdx.x;
  int t = threadIdx.x;
  __shared__ float sh[256];
  float v = loadf(q, (size_t)row * EMBED + t, fl);
  sh[t] = v;
  __syncthreads();
  for (int s = 128; s > 0; s >>= 1) { if (t < s) sh[t] += sh[t + s]; __syncthreads(); }
  float mu = sh[0] * (1.f / 256.f);
  __syncthreads();
  float xc = v - mu;
  sh[t] = xc * xc;
  __syncthreads();
  for (int s = 128; s > 0; s >>= 1) { if (t < s) sh[t] += sh[t + s]; __syncthreads(); }
  float r = rsqrtf(sh[0] * (1.f / 256.f) + LN_EPS);
  out[(size_t)row * EMBED + t] = f2bu(xc * r * loadf(g, t, fl) + loadf(be, t, fl));
}

// ---------------- MFMA GEMM, double-buffered staging, direct stores ----------------
// C[M,N] = A[M,K] @ Bt[N,K]^T (+bias)(+resid). 128x128 tile, 4 waves, BK=32.
// ABF: A bf16 (cp16 DMA). else: A flag-dtype (VGPR load early, convert+ds_write late).
// OUTMODE: 0 fp32, 1 bf16, 2 flag. BiasC: 0 bias fp32, 2 bias flag dtype.
template <int OUTMODE, bool ABF>
__global__ __launch_bounds__(256) void mfma_gemm(const void* __restrict__ A,
                                                 const u16* __restrict__ Bt,
                                                 const void* __restrict__ bias, int BiasC,
                                                 const void* __restrict__ resid,
                                                 void* __restrict__ Cv,
                                                 int M, int N, int K,
                                                 const int* __restrict__ dflag) {
  int fl = *dflag;
  __shared__ u16 As[2][4096];
  __shared__ u16 Bs[2][4096];
  int tid = threadIdx.x;
  int m0 = blockIdx.x * 128, n0 = blockIdx.y * 128;
  int wave = tid >> 6, lane = tid & 63;
  int quad = lane >> 4, r16 = lane & 15;
  int wm = (wave >> 1) * 64, wn = (wave & 1) * 64;

  f32x4 acc[4][4];
#pragma unroll
  for (int i = 0; i < 4; i++)
#pragma unroll
    for (int j = 0; j < 4; j++) acc[i][j] = (f32x4){0.f, 0.f, 0.f, 0.f};

  int p0 = tid, p1 = tid + 256;
  int r0 = p0 >> 2, c0 = (p0 & 3) * 8;
  int r1 = p1 >> 2, c1 = (p1 & 3) * 8;
  int ra0 = imin(m0 + r0, M - 1), ra1 = imin(m0 + r1, M - 1);

  const u16*   Ab = (const u16*)A;
  const float* Af = (const float*)A;

  // ---- initial stage into buffer 0 (tile k=0) ----
  if (ABF) {
    cp16(Ab + (size_t)ra0 * K + c0, &As[0][p0 * 8]);
    cp16(Ab + (size_t)ra1 * K + c1, &As[0][p1 * 8]);
  } else if (fl) {
    *(int4*)&As[0][p0 * 8] = *(const int4*)(Ab + (size_t)ra0 * K + c0);
    *(int4*)&As[0][p1 * 8] = *(const int4*)(Ab + (size_t)ra1 * K + c1);
  } else {
    float4 f00 = *(const float4*)(Af + (size_t)ra0 * K + c0);
    float4 f01 = *(const float4*)(Af + (size_t)ra0 * K + c0 + 4);
    float4 f10 = *(const float4*)(Af + (size_t)ra1 * K + c1);
    float4 f11 = *(const float4*)(Af + (size_t)ra1 * K + c1 + 4);
    u16* d0 = &As[0][p0 * 8];
    d0[0] = f2bu(f00.x); d0[1] = f2bu(f00.y); d0[2] = f2bu(f00.z); d0[3] = f2bu(f00.w);
    d0[4] = f2bu(f01.x); d0[5] = f2bu(f01.y); d0[6] = f2bu(f01.z); d0[7] = f2bu(f01.w);
    u16* d1 = &As[0][p1 * 8];
    d1[0] = f2bu(f10.x); d1[1] = f2bu(f10.y); d1[2] = f2bu(f10.z); d1[3] = f2bu(f10.w);
    d1[4] = f2bu(f11.x); d1[5] = f2bu(f11.y); d1[6] = f2bu(f11.z); d1[7] = f2bu(f11.w);
  }
  cp16(Bt + (size_t)(n0 + r0) * K + c0, &Bs[0][p0 * 8]);
  cp16(Bt + (size_t)(n0 + r1) * K + c1, &Bs[0][p1 * 8]);

  int cur = 0;
  for (int k0 = 0; k0 < K; k0 += 32) {
    // Barrier guarantees: (a) buf[cur]'s staging (DMA/ds_write) complete,
    // (b) all waves' reads of buf[cur^1] from the previous iter complete,
    // so writing buf[cur^1] below is safe.
    __syncthreads();
    int kn = k0 + 32;
    bool pf = kn < K;
    float4 f00, f01, f10, f11;   // !ABF,!fl prefetch regs
    int4 i0v, i1v;               // !ABF,fl prefetch regs
    if (pf) {
      if (ABF) {
        cp16(Ab + (size_t)ra0 * K + kn + c0, &As[cur ^ 1][p0 * 8]);
        cp16(Ab + (size_t)ra1 * K + kn + c1, &As[cur ^ 1][p1 * 8]);
      } else if (fl) {
        i0v = *(const int4*)(Ab + (size_t)ra0 * K + kn + c0);
        i1v = *(const int4*)(Ab + (size_t)ra1 * K + kn + c1);
      } else {
        f00 = *(const float4*)(Af + (size_t)ra0 * K + kn + c0);
        f01 = *(const float4*)(Af + (size_t)ra0 * K + kn + c0 + 4);
        f10 = *(const float4*)(Af + (size_t)ra1 * K + kn + c1);
        f11 = *(const float4*)(Af + (size_t)ra1 * K + kn + c1 + 4);
      }
      cp16(Bt + (size_t)(n0 + r0) * K + kn + c0, &Bs[cur ^ 1][p0 * 8]);
      cp16(Bt + (size_t)(n0 + r1) * K + kn + c1, &Bs[cur ^ 1][p1 * 8]);
    }

    bf16x8v a[4], b[4];
#pragma unroll
    for (int i = 0; i < 4; i++)
      a[i] = *(const bf16x8v*)&As[cur][(wm + i * 16 + r16) * 32 + quad * 8];
#pragma unroll
    for (int j = 0; j < 4; j++)
      b[j] = *(const bf16x8v*)&Bs[cur][(wn + j * 16 + r16) * 32 + quad * 8];
#pragma unroll
    for (int i = 0; i < 4; i++)
#pragma unroll
      for (int j = 0; j < 4; j++)
        acc[i][j] = __builtin_amdgcn_mfma_f32_16x16x32_bf16(a[i], b[j], acc[i][j], 0, 0, 0);

    if (pf && !ABF) {   // commit prefetched A after compute (overlaps load latency)
      if (fl) {
        *(int4*)&As[cur ^ 1][p0 * 8] = i0v;
        *(int4*)&As[cur ^ 1][p1 * 8] = i1v;
      } else {
        u16* d0 = &As[cur ^ 1][p0 * 8];
        d0[0] = f2bu(f00.x); d0[1] = f2bu(f00.y); d0[2] = f2bu(f00.z); d0[3] = f2bu(f00.w);
        d0[4] = f2bu(f01.x); d0[5] = f2bu(f01.y); d0[6] = f2bu(f01.z); d0[7] = f2bu(f01.w);
        u16* d1 = &As[cur ^ 1][p1 * 8];
        d1[0] = f2bu(f10.x); d1[1] = f2bu(f10.y); d1[2] = f2bu(f10.z); d1[3] = f2bu(f10.w);
        d1[4] = f2bu(f11.x); d1[5] = f2bu(f11.y); d1[6] = f2bu(f11.z); d1[7] = f2bu(f11.w);
      }
    }
    cur ^= 1;
  }

  // ---- epilogue: direct global stores (round-3 proven) ----
  int obf = (OUTMODE == 2) ? fl : OUTMODE;
  int bfl = (BiasC == 2) ? fl : 0;
#pragma unroll
  for (int j = 0; j < 4; j++) {
    int col = n0 + wn + j * 16 + r16;
    float bv = bias ? loadf(bias, col, bfl) : 0.f;
#pragma unroll
    for (int i = 0; i < 4; i++) {
#pragma unroll
      for (int reg = 0; reg < 4; reg++) {
        int row = m0 + wm + i * 16 + quad * 4 + reg;
        if (row < M) {
          float v = acc[i][j][reg] + bv;
          if (resid) v += loadf(resid, (size_t)row * N + col, fl);
          if (obf) ((u16*)Cv)[(size_t)row * N + col] = f2bu(v);
          else     ((float*)Cv)[(size_t)row * N + col] = v;
        }
      }
    }
  }
}

// ---------------- Deformable sampling v2 (oa buffer: row stride 384) ----------------
__global__ __launch_bounds__(256) void sample2_kernel(const float* __restrict__ oa,
                                                      const void* __restrict__ qsp,
                                                      const int* __restrict__ qbo, int nb,
                                                      const int* __restrict__ lss,
                                                      const u16* __restrict__ value,
                                                      u16* __restrict__ samp, int Qn,
                                                      const int* __restrict__ dflag) {
  int fl = *dflag;
  int t = threadIdx.x;
  int q2 = t >> 7;
  int i7 = t & 127;
  int qb = blockIdx.x * 2;
  int q = imin(qb + q2, Qn - 1);

  __shared__ float Loff[2][256];
  __shared__ float Lw[2][128];
  __shared__ int   Lb[2];
  __shared__ int   Co[2][128][4];
  __shared__ float Cw[2][128][4];

  {
    const float* row = oa + (size_t)q * 384;
    float2 v = ((const float2*)row)[i7];
    Loff[q2][i7 * 2]     = v.x;
    Loff[q2][i7 * 2 + 1] = v.y;
    Lw[q2][i7] = row[256 + i7];
  }
  if (t < 2) {
    int qq = imin(qb + t, Qn - 1);
    int b = 0;
    for (int i = 1; i < nb; i++) if (qq >= qbo[i]) b = i;
    Lb[t] = b;
  }
  __syncthreads();

  if (t < 16) {
    int sq = t >> 3, h = t & 7;
    float* w = &Lw[sq][h * 16];
    float mx = w[0];
    for (int i = 1; i < 16; i++) mx = fmaxf(mx, w[i]);
    float s = 0.f;
    for (int i = 0; i < 16; i++) { float e = __expf(w[i] - mx); w[i] = e; s += e; }
    float inv = 1.f / s;
    for (int i = 0; i < 16; i++) w[i] *= inv;
  }
  __syncthreads();

  {
    int h = i7 >> 4, lp = i7 & 15, l = lp >> 2;
    int Hi = lss[l * 2], Wi = lss[l * 2 + 1];
    float Hl = (float)Hi, Wl = (float)Wi;
    float qy = loadf(qsp, (size_t)q * 2, fl);
    float qx = loadf(qsp, (size_t)q * 2 + 1, fl);
    float a  = Lw[q2][i7];
    float oy = Loff[q2][i7 * 2], ox = Loff[q2][i7 * 2 + 1];
    float py = (qy + oy / Hl) * Hl - 0.5f;
    float px = (qx + ox / Wl) * Wl - 0.5f;
    float y0f = floorf(py), x0f = floorf(px);
    float wy = py - y0f, wx = px - x0f;
    int y0 = (int)y0f, x0 = (int)x0f;
    int bbase = Lb[q2] * (HPAD * WPAD * LEVELS * EMBED);
#pragma unroll
    for (int c = 0; c < 4; c++) {
      int yi = y0 + (c >> 1), xi = x0 + (c & 1);
      float w = ((c >> 1) ? wy : 1.f - wy) * ((c & 1) ? wx : 1.f - wx);
      bool ok = (yi >= 0) & (yi < Hi) & (xi >= 0) & (xi < Wi);
      Co[q2][i7][c] = ok ? (bbase + ((yi * WPAD + xi) * LEVELS + l) * EMBED + h * HEAD_DIM) : 0;
      Cw[q2][i7][c] = ok ? (a * w) : 0.f;
    }
  }
  __syncthreads();

  {
    int h = (t >> 4) & 7;
    int d2 = t & 15;
    float ax = 0.f, ay = 0.f;
#pragma unroll
    for (int lp = 0; lp < 16; lp++) {
      int4   o4 = *(const int4*)&Co[q2][h * 16 + lp][0];
      float4 w4 = *(const float4*)&Cw[q2][h * 16 + lp][0];
      unsigned v;
      v = *(const unsigned*)(value + o4.x + d2 * 2);
      ax += w4.x * __uint_as_float(v << 16); ay += w4.x * __uint_as_float(v & 0xffff0000u);
      v = *(const unsigned*)(value + o4.y + d2 * 2);
      ax += w4.y * __uint_as_float(v << 16); ay += w4.y * __uint_as_float(v & 0xffff0000u);
      v = *(const unsigned*)(value + o4.z + d2 * 2);
      ax += w4.z * __uint_as_float(v << 16); ay += w4.z * __uint_as_float(v & 0xffff0000u);
      v = *(const unsigned*)(value + o4.w + d2 * 2);
      ax += w4.w * __uint_as_float(v << 16); ay += w4.w * __uint_as_float(v & 0xffff0000u);
    }
    if (qb + q2 < Qn) {
      unsigned pk = (unsigned)f2bu(ax) | ((unsigned)f2bu(ay) << 16);
      *(unsigned*)(samp + (size_t)(qb + q2) * 256 + h * 32 + d2 * 2) = pk;
    }
  }
}

extern "C" void kernel_launch(void* const* d_in, const int* in_sizes, int n_in,
                              void* d_out, int out_size, void* d_ws, size_t ws_size,
                              hipStream_t stream) {
  const void* query  = d_in[0];
  const void* qsp    = d_in[1];
  const int*  qbo    = (const int*)d_in[2];
  const void* sfm    = d_in[3];
  const int*  lss    = (const int*)d_in[4];
  const void* gamma  = d_in[5];
  const void* beta   = d_in[6];
  const void* W_q    = d_in[7];
  const void* W_off  = d_in[8];
  const void* b_off  = d_in[9];
  const void* W_attn = d_in[10];
  const void* b_attn = d_in[11];
  const void* W_val  = d_in[12];
  const void* b_val  = d_in[13];
  const void* W_out  = d_in[14];

  const int Q  = in_sizes[0] / EMBED;      // 20000
  const int nb = in_sizes[2] - 1;          // 2
  const int MV = in_sizes[3] / EMBED;      // 131072

  char* ws = (char*)d_ws;
  size_t o = 0;
  auto alloc = [&](size_t bytes) { size_t r = o; o = (o + bytes + 255) & ~(size_t)255; return r; };
  u16*   xln   = (u16*)(ws + alloc((size_t)Q * EMBED * sizeof(u16)));
  u16*   x     = (u16*)(ws + alloc((size_t)Q * EMBED * sizeof(u16)));
  float* oaw   = (float*)(ws + alloc((size_t)Q * 384 * sizeof(float)));
  u16*   valw  = (u16*)(ws + alloc((size_t)MV * EMBED * sizeof(u16)));
  u16*   sampw = (u16*)(ws + alloc((size_t)Q * EMBED * sizeof(u16)));
  u16*   wtq   = (u16*)(ws + alloc(256 * 256 * sizeof(u16)));
  u16*   wtoa  = (u16*)(ws + alloc(384 * 256 * sizeof(u16)));
  u16*   wtval = (u16*)(ws + alloc(256 * 256 * sizeof(u16)));
  u16*   wtout = (u16*)(ws + alloc(256 * 256 * sizeof(u16)));
  float* boa   = (float*)(ws + alloc(384 * sizeof(float)));
  int*   dflag = (int*)(ws + alloc(256));
  (void)ws_size;

  // 0) dtype probe + bias combine
  detect_kernel<<<1, 256, 0, stream>>>((const unsigned*)query, dflag);
  boa_kernel<<<1, 384, 0, stream>>>(b_off, b_attn, boa, dflag);

  // 0b) coalesced weight transposes to bf16 [N][K]
  wtrans_kernel<<<dim3(8, 8), 256, 0, stream>>>(W_q,    wtq,              256, 256, dflag);
  wtrans_kernel<<<dim3(8, 8), 256, 0, stream>>>(W_off,  wtoa,             256, 256, dflag);
  wtrans_kernel<<<dim3(8, 4), 256, 0, stream>>>(W_attn, wtoa + 256 * 256, 256, 128, dflag);
  wtrans_kernel<<<dim3(8, 8), 256, 0, stream>>>(W_val,  wtval,            256, 256, dflag);
  wtrans_kernel<<<dim3(8, 8), 256, 0, stream>>>(W_out,  wtout,            256, 256, dflag);

  // 1) LayerNorm -> bf16
  ln_kernel<<<Q, 256, 0, stream>>>(query, gamma, beta, xln, dflag);

  const int GQ = (Q + 127) / 128;
  // 2) x = xln @ W_q   (bf16 out)
  mfma_gemm<1, true><<<dim3(GQ, 2), 256, 0, stream>>>(xln, wtq, nullptr, 0, nullptr, x, Q, 256, 256, dflag);
  // 3+4) [off|attn] = x @ [W_off|W_attn] + [b_off|b_attn]  (fp32 out, N=384)
  mfma_gemm<0, true><<<dim3(GQ, 3), 256, 0, stream>>>(x, wtoa, boa, 0, nullptr, oaw, Q, 384, 256, dflag);
  // 5) value = sfm @ W_val + b_val  (bf16 out; fp32 A converted in staging)
  mfma_gemm<1, false><<<dim3(MV / 128, 2), 256, 0, stream>>>(sfm, wtval, b_val, 2, nullptr, valw, MV, 256, 256, dflag);
  // 6) sampling (bf16 out)
  sample2_kernel<<<(Q + 1) / 2, 256, 0, stream>>>(oaw, qsp, qbo, nb, lss, valw, sampw, Q, dflag);
  // 7) out = sampw @ W_out + residual(query)  (flag dtype out)
  mfma_gemm<2, true><<<dim3(GQ, 2), 256, 0, stream>>>(sampw, wtout, nullptr, 0, query, d_out, Q, 256, 256, dflag);
}

// Round 6
// 431.776 us; speedup vs baseline: 1.1388x; 1.1388x over previous
//
#include <hip/hip_runtime.h>
#include <hip/hip_bf16.h>
#include <stdint.h>

#define EMBED 256
#define HEADS 8
#define LEVELS 4
#define POINTS 4
#define HEAD_DIM 32
#define HPAD 128
#define WPAD 128
#define LN_EPS 1e-5f

typedef unsigned short u16;
typedef __attribute__((ext_vector_type(8))) short bf16x8v;
typedef __attribute__((ext_vector_type(4))) float f32x4;

static __device__ __forceinline__ float bu2f(u16 u) {
  return __uint_as_float(((unsigned)u) << 16);
}
static __device__ __forceinline__ u16 f2bu(float f) {   // fp32 -> bf16 RNE
  unsigned x = __float_as_uint(f);
  return (u16)((x + 0x7fffu + ((x >> 16) & 1u)) >> 16);
}
static __device__ __forceinline__ float loadf(const void* p, size_t i, int isbf) {
  return isbf ? bu2f(((const u16*)p)[i]) : ((const float*)p)[i];
}
static __device__ __forceinline__ int imin(int a, int b) { return a < b ? a : b; }

static __device__ __forceinline__ void cp16(const u16* g, u16* l) {
  __builtin_amdgcn_global_load_lds((const __attribute__((address_space(1))) unsigned*)g,
                                   (__attribute__((address_space(3))) unsigned*)l, 16, 0, 0);
}

// ------------- dtype probe -------------
__global__ __launch_bounds__(256) void detect_kernel(const unsigned* __restrict__ q,
                                                     int* __restrict__ flag) {
  int t = threadIdx.x;
  __shared__ int s[256];
  unsigned u = q[t * 13 + 1];
  unsigned e = (u >> 7) & 0xFF;
  s[t] = (e >= 116 && e <= 130) ? 1 : 0;
  __syncthreads();
  for (int st = 128; st > 0; st >>= 1) { if (t < st) s[t] += s[t + st]; __syncthreads(); }
  if (t == 0) *flag = (s[0] > 200) ? 1 : 0;   // 1 => bf16 elements
}

// ------------- combined off/attn bias (fp32) -------------
__global__ __launch_bounds__(384) void boa_kernel(const void* __restrict__ b_off,
                                                  const void* __restrict__ b_attn,
                                                  float* __restrict__ boa,
                                                  const int* __restrict__ dflag) {
  int fl = *dflag;
  int t = threadIdx.x;
  boa[t] = (t < 256) ? loadf(b_off, t, fl) : loadf(b_attn, t - 256, fl);
}

// ------------- coalesced tiled transpose: Wt[n*K+k] = bf16(W[k*N+n]) -------------
__global__ __launch_bounds__(256) void wtrans_kernel(const void* __restrict__ W,
                                                     u16* __restrict__ Wt,
                                                     int K, int N,
                                                     const int* __restrict__ dflag) {
  int fl = *dflag;
  __shared__ float tile[32][33];
  int tx = threadIdx.x & 31, ty = threadIdx.x >> 5;
  int k0 = blockIdx.x * 32, n0 = blockIdx.y * 32;
#pragma unroll
  for (int j = 0; j < 4; j++) {
    int r = ty + j * 8;
    tile[r][tx] = loadf(W, (size_t)(k0 + r) * N + n0 + tx, fl);
  }
  __syncthreads();
#pragma unroll
  for (int j = 0; j < 4; j++) {
    int n = ty + j * 8;
    Wt[(size_t)(n0 + n) * K + k0 + tx] = f2bu(tile[tx][n]);
  }
}

// ---------------- LayerNorm ----------------
__global__ __launch_bounds__(256) void ln_kernel(const void* __restrict__ q,
                                                 const void* __restrict__ g,
                                                 const void* __restrict__ be,
                                                 u16* __restrict__ out,
                                                 const int* __restrict__ dflag) {
  int fl = *dflag;
  int row = blockIdx.x;
  int t = threadIdx.x;
  __shared__ float sh[256];
  float v = loadf(q, (size_t)row * EMBED + t, fl);
  sh[t] = v;
  __syncthreads();
  for (int s = 128; s > 0; s >>= 1) { if (t < s) sh[t] += sh[t + s]; __syncthreads(); }
  float mu = sh[0] * (1.f / 256.f);
  __syncthreads();
  float xc = v - mu;
  sh[t] = xc * xc;
  __syncthreads();
  for (int s = 128; s > 0; s >>= 1) { if (t < s) sh[t] += sh[t + s]; __syncthreads(); }
  float r = rsqrtf(sh[0] * (1.f / 256.f) + LN_EPS);
  out[(size_t)row * EMBED + t] = f2bu(xc * r * loadf(g, t, fl) + loadf(be, t, fl));
}

// ---------------- MFMA GEMM, single-buffer staging (round-3), shfl-packed stores ----
// C[M,N] = A[M,K] @ Bt[N,K]^T (+bias)(+resid). 128x128 tile, 4 waves, BK=32.
// ABF: A bf16 (cp16 DMA). else: A flag-dtype (VGPR convert staging).
// OUTMODE: 0 fp32, 1 bf16, 2 flag. BiasC: 0 bias fp32, 2 bias flag dtype.
template <int OUTMODE, bool ABF>
__global__ __launch_bounds__(256) void mfma_gemm(const void* __restrict__ A,
                                                 const u16* __restrict__ Bt,
                                                 const void* __restrict__ bias, int BiasC,
                                                 const void* __restrict__ resid,
                                                 void* __restrict__ Cv,
                                                 int M, int N, int K,
                                                 const int* __restrict__ dflag) {
  int fl = *dflag;
  __shared__ u16 As[4096];
  __shared__ u16 Bs[4096];
  int tid = threadIdx.x;
  int m0 = blockIdx.x * 128, n0 = blockIdx.y * 128;
  int wave = tid >> 6, lane = tid & 63;
  int quad = lane >> 4, r16 = lane & 15;
  int wm = (wave >> 1) * 64, wn = (wave & 1) * 64;

  f32x4 acc[4][4];
#pragma unroll
  for (int i = 0; i < 4; i++)
#pragma unroll
    for (int j = 0; j < 4; j++) acc[i][j] = (f32x4){0.f, 0.f, 0.f, 0.f};

  int p0 = tid, p1 = tid + 256;
  int r0 = p0 >> 2, c0 = (p0 & 3) * 8;
  int r1 = p1 >> 2, c1 = (p1 & 3) * 8;
  int ra0 = imin(m0 + r0, M - 1), ra1 = imin(m0 + r1, M - 1);

  const u16*   Ab = (const u16*)A;
  const float* Af = (const float*)A;

  for (int k0 = 0; k0 < K; k0 += 32) {
    __syncthreads();   // previous iteration's LDS reads complete
    if (ABF) {
      cp16(Ab + (size_t)ra0 * K + k0 + c0, &As[p0 * 8]);
      cp16(Ab + (size_t)ra1 * K + k0 + c1, &As[p1 * 8]);
    } else if (fl) {
      *(int4*)&As[p0 * 8] = *(const int4*)(Ab + (size_t)ra0 * K + k0 + c0);
      *(int4*)&As[p1 * 8] = *(const int4*)(Ab + (size_t)ra1 * K + k0 + c1);
    } else {
      float4 f00 = *(const float4*)(Af + (size_t)ra0 * K + k0 + c0);
      float4 f01 = *(const float4*)(Af + (size_t)ra0 * K + k0 + c0 + 4);
      float4 f10 = *(const float4*)(Af + (size_t)ra1 * K + k0 + c1);
      float4 f11 = *(const float4*)(Af + (size_t)ra1 * K + k0 + c1 + 4);
      u16* d0 = &As[p0 * 8];
      d0[0] = f2bu(f00.x); d0[1] = f2bu(f00.y); d0[2] = f2bu(f00.z); d0[3] = f2bu(f00.w);
      d0[4] = f2bu(f01.x); d0[5] = f2bu(f01.y); d0[6] = f2bu(f01.z); d0[7] = f2bu(f01.w);
      u16* d1 = &As[p1 * 8];
      d1[0] = f2bu(f10.x); d1[1] = f2bu(f10.y); d1[2] = f2bu(f10.z); d1[3] = f2bu(f10.w);
      d1[4] = f2bu(f11.x); d1[5] = f2bu(f11.y); d1[6] = f2bu(f11.z); d1[7] = f2bu(f11.w);
    }
    cp16(Bt + (size_t)(n0 + r0) * K + k0 + c0, &Bs[p0 * 8]);
    cp16(Bt + (size_t)(n0 + r1) * K + k0 + c1, &Bs[p1 * 8]);
    __syncthreads();

    bf16x8v a[4], b[4];
#pragma unroll
    for (int i = 0; i < 4; i++)
      a[i] = *(const bf16x8v*)&As[(wm + i * 16 + r16) * 32 + quad * 8];
#pragma unroll
    for (int j = 0; j < 4; j++)
      b[j] = *(const bf16x8v*)&Bs[(wn + j * 16 + r16) * 32 + quad * 8];
#pragma unroll
    for (int i = 0; i < 4; i++)
#pragma unroll
      for (int j = 0; j < 4; j++)
        acc[i][j] = __builtin_amdgcn_mfma_f32_16x16x32_bf16(a[i], b[j], acc[i][j], 0, 0, 0);
  }

  // ---- epilogue ----
  int obf = (OUTMODE == 2) ? fl : OUTMODE;
  int bfl = (BiasC == 2) ? fl : 0;
  if (bias) {   // bias added in source (pre-shuffle) layout: col = n0+wn+j*16+r16
#pragma unroll
    for (int j = 0; j < 4; j++) {
      float bv = loadf(bias, n0 + wn + j * 16 + r16, bfl);
#pragma unroll
      for (int i = 0; i < 4; i++)
#pragma unroll
        for (int reg = 0; reg < 4; reg++) acc[i][j][reg] += bv;
    }
  }

  if (obf) {
    // shuffle-pack: lane L takes cols 2*r16, 2*r16+1 of the jp-th 32-col group from
    // lanes (quad<<4)|((2*r16)&15) (+1); j-pair selected by r16<8. Rows preserved
    // (same quad). Result: 16 lanes x 4 B = 64 B fully-dirty lines per quad-row.
    int sl0 = (quad << 4) | ((2 * r16) & 15);
    int sl1 = sl0 + 1;
    bool lohalf = (r16 < 8);
#pragma unroll
    for (int i = 0; i < 4; i++) {
#pragma unroll
      for (int jp = 0; jp < 2; jp++) {
#pragma unroll
        for (int reg = 0; reg < 4; reg++) {
          float vA = acc[i][jp * 2][reg], vB = acc[i][jp * 2 + 1][reg];
          float a0 = __shfl(vA, sl0), a1 = __shfl(vA, sl1);
          float b0 = __shfl(vB, sl0), b1 = __shfl(vB, sl1);
          float lo = lohalf ? a0 : b0;
          float hi = lohalf ? a1 : b1;
          int row = m0 + wm + i * 16 + quad * 4 + reg;
          if (row < M) {
            size_t base = (size_t)row * N + n0 + wn + jp * 32 + 2 * r16;
            if (resid) {
              lo += loadf(resid, base, fl);
              hi += loadf(resid, base + 1, fl);
            }
            unsigned pk = (unsigned)f2bu(lo) | ((unsigned)f2bu(hi) << 16);
            *(unsigned*)((u16*)Cv + base) = pk;
          }
        }
      }
    }
  } else {
    // fp32 direct stores: 16 lanes x 4 B = 64 B contiguous already
#pragma unroll
    for (int j = 0; j < 4; j++) {
      int col = n0 + wn + j * 16 + r16;
#pragma unroll
      for (int i = 0; i < 4; i++) {
#pragma unroll
        for (int reg = 0; reg < 4; reg++) {
          int row = m0 + wm + i * 16 + quad * 4 + reg;
          if (row < M) {
            float v = acc[i][j][reg];
            if (resid) v += loadf(resid, (size_t)row * N + col, fl);
            ((float*)Cv)[(size_t)row * N + col] = v;
          }
        }
      }
    }
  }
}

// ---------------- Deformable sampling v2 (oa buffer: row stride 384) ----------------
__global__ __launch_bounds__(256) void sample2_kernel(const float* __restrict__ oa,
                                                      const void* __restrict__ qsp,
                                                      const int* __restrict__ qbo, int nb,
                                                      const int* __restrict__ lss,
                                                      const u16* __restrict__ value,
                                                      u16* __restrict__ samp, int Qn,
                                                      const int* __restrict__ dflag) {
  int fl = *dflag;
  int t = threadIdx.x;
  int q2 = t >> 7;
  int i7 = t & 127;
  int qb = blockIdx.x * 2;
  int q = imin(qb + q2, Qn - 1);

  __shared__ float Loff[2][256];
  __shared__ float Lw[2][128];
  __shared__ int   Lb[2];
  __shared__ int   Co[2][128][4];
  __shared__ float Cw[2][128][4];

  {
    const float* row = oa + (size_t)q * 384;
    float2 v = ((const float2*)row)[i7];
    Loff[q2][i7 * 2]     = v.x;
    Loff[q2][i7 * 2 + 1] = v.y;
    Lw[q2][i7] = row[256 + i7];
  }
  if (t < 2) {
    int qq = imin(qb + t, Qn - 1);
    int b = 0;
    for (int i = 1; i < nb; i++) if (qq >= qbo[i]) b = i;
    Lb[t] = b;
  }
  __syncthreads();

  if (t < 16) {
    int sq = t >> 3, h = t & 7;
    float* w = &Lw[sq][h * 16];
    float mx = w[0];
    for (int i = 1; i < 16; i++) mx = fmaxf(mx, w[i]);
    float s = 0.f;
    for (int i = 0; i < 16; i++) { float e = __expf(w[i] - mx); w[i] = e; s += e; }
    float inv = 1.f / s;
    for (int i = 0; i < 16; i++) w[i] *= inv;
  }
  __syncthreads();

  {
    int h = i7 >> 4, lp = i7 & 15, l = lp >> 2;
    int Hi = lss[l * 2], Wi = lss[l * 2 + 1];
    float Hl = (float)Hi, Wl = (float)Wi;
    float qy = loadf(qsp, (size_t)q * 2, fl);
    float qx = loadf(qsp, (size_t)q * 2 + 1, fl);
    float a  = Lw[q2][i7];
    float oy = Loff[q2][i7 * 2], ox = Loff[q2][i7 * 2 + 1];
    float py = (qy + oy / Hl) * Hl - 0.5f;
    float px = (qx + ox / Wl) * Wl - 0.5f;
    float y0f = floorf(py), x0f = floorf(px);
    float wy = py - y0f, wx = px - x0f;
    int y0 = (int)y0f, x0 = (int)x0f;
    int bbase = Lb[q2] * (HPAD * WPAD * LEVELS * EMBED);
#pragma unroll
    for (int c = 0; c < 4; c++) {
      int yi = y0 + (c >> 1), xi = x0 + (c & 1);
      float w = ((c >> 1) ? wy : 1.f - wy) * ((c & 1) ? wx : 1.f - wx);
      bool ok = (yi >= 0) & (yi < Hi) & (xi >= 0) & (xi < Wi);
      Co[q2][i7][c] = ok ? (bbase + ((yi * WPAD + xi) * LEVELS + l) * EMBED + h * HEAD_DIM) : 0;
      Cw[q2][i7][c] = ok ? (a * w) : 0.f;
    }
  }
  __syncthreads();

  {
    int h = (t >> 4) & 7;
    int d2 = t & 15;
    float ax = 0.f, ay = 0.f;
#pragma unroll
    for (int lp = 0; lp < 16; lp++) {
      int4   o4 = *(const int4*)&Co[q2][h * 16 + lp][0];
      float4 w4 = *(const float4*)&Cw[q2][h * 16 + lp][0];
      unsigned v;
      v = *(const unsigned*)(value + o4.x + d2 * 2);
      ax += w4.x * __uint_as_float(v << 16); ay += w4.x * __uint_as_float(v & 0xffff0000u);
      v = *(const unsigned*)(value + o4.y + d2 * 2);
      ax += w4.y * __uint_as_float(v << 16); ay += w4.y * __uint_as_float(v & 0xffff0000u);
      v = *(const unsigned*)(value + o4.z + d2 * 2);
      ax += w4.z * __uint_as_float(v << 16); ay += w4.z * __uint_as_float(v & 0xffff0000u);
      v = *(const unsigned*)(value + o4.w + d2 * 2);
      ax += w4.w * __uint_as_float(v << 16); ay += w4.w * __uint_as_float(v & 0xffff0000u);
    }
    if (qb + q2 < Qn) {
      unsigned pk = (unsigned)f2bu(ax) | ((unsigned)f2bu(ay) << 16);
      *(unsigned*)(samp + (size_t)(qb + q2) * 256 + h * 32 + d2 * 2) = pk;
    }
  }
}

extern "C" void kernel_launch(void* const* d_in, const int* in_sizes, int n_in,
                              void* d_out, int out_size, void* d_ws, size_t ws_size,
                              hipStream_t stream) {
  const void* query  = d_in[0];
  const void* qsp    = d_in[1];
  const int*  qbo    = (const int*)d_in[2];
  const void* sfm    = d_in[3];
  const int*  lss    = (const int*)d_in[4];
  const void* gamma  = d_in[5];
  const void* beta   = d_in[6];
  const void* W_q    = d_in[7];
  const void* W_off  = d_in[8];
  const void* b_off  = d_in[9];
  const void* W_attn = d_in[10];
  const void* b_attn = d_in[11];
  const void* W_val  = d_in[12];
  const void* b_val  = d_in[13];
  const void* W_out  = d_in[14];

  const int Q  = in_sizes[0] / EMBED;      // 20000
  const int nb = in_sizes[2] - 1;          // 2
  const int MV = in_sizes[3] / EMBED;      // 131072

  char* ws = (char*)d_ws;
  size_t o = 0;
  auto alloc = [&](size_t bytes) { size_t r = o; o = (o + bytes + 255) & ~(size_t)255; return r; };
  u16*   xln   = (u16*)(ws + alloc((size_t)Q * EMBED * sizeof(u16)));
  u16*   x     = (u16*)(ws + alloc((size_t)Q * EMBED * sizeof(u16)));
  float* oaw   = (float*)(ws + alloc((size_t)Q * 384 * sizeof(float)));
  u16*   valw  = (u16*)(ws + alloc((size_t)MV * EMBED * sizeof(u16)));
  u16*   sampw = (u16*)(ws + alloc((size_t)Q * EMBED * sizeof(u16)));
  u16*   wtq   = (u16*)(ws + alloc(256 * 256 * sizeof(u16)));
  u16*   wtoa  = (u16*)(ws + alloc(384 * 256 * sizeof(u16)));
  u16*   wtval = (u16*)(ws + alloc(256 * 256 * sizeof(u16)));
  u16*   wtout = (u16*)(ws + alloc(256 * 256 * sizeof(u16)));
  float* boa   = (float*)(ws + alloc(384 * sizeof(float)));
  int*   dflag = (int*)(ws + alloc(256));
  (void)ws_size;

  // 0) dtype probe + bias combine
  detect_kernel<<<1, 256, 0, stream>>>((const unsigned*)query, dflag);
  boa_kernel<<<1, 384, 0, stream>>>(b_off, b_attn, boa, dflag);

  // 0b) coalesced weight transposes to bf16 [N][K]
  wtrans_kernel<<<dim3(8, 8), 256, 0, stream>>>(W_q,    wtq,              256, 256, dflag);
  wtrans_kernel<<<dim3(8, 8), 256, 0, stream>>>(W_off,  wtoa,             256, 256, dflag);
  wtrans_kernel<<<dim3(8, 4), 256, 0, stream>>>(W_attn, wtoa + 256 * 256, 256, 128, dflag);
  wtrans_kernel<<<dim3(8, 8), 256, 0, stream>>>(W_val,  wtval,            256, 256, dflag);
  wtrans_kernel<<<dim3(8, 8), 256, 0, stream>>>(W_out,  wtout,            256, 256, dflag);

  // 1) LayerNorm -> bf16
  ln_kernel<<<Q, 256, 0, stream>>>(query, gamma, beta, xln, dflag);

  const int GQ = (Q + 127) / 128;
  // 2) x = xln @ W_q   (bf16 out)
  mfma_gemm<1, true><<<dim3(GQ, 2), 256, 0, stream>>>(xln, wtq, nullptr, 0, nullptr, x, Q, 256, 256, dflag);
  // 3+4) [off|attn] = x @ [W_off|W_attn] + [b_off|b_attn]  (fp32 out, N=384)
  mfma_gemm<0, true><<<dim3(GQ, 3), 256, 0, stream>>>(x, wtoa, boa, 0, nullptr, oaw, Q, 384, 256, dflag);
  // 5) value = sfm @ W_val + b_val  (bf16 out; fp32 A converted in staging)
  mfma_gemm<1, false><<<dim3(MV / 128, 2), 256, 0, stream>>>(sfm, wtval, b_val, 2, nullptr, valw, MV, 256, 256, dflag);
  // 6) sampling (bf16 out)
  sample2_kernel<<<(Q + 1) / 2, 256, 0, stream>>>(oaw, qsp, qbo, nb, lss, valw, sampw, Q, dflag);
  // 7) out = sampw @ W_out + residual(query)  (flag dtype out)
  mfma_gemm<2, true><<<dim3(GQ, 2), 256, 0, stream>>>(sampw, wtout, nullptr, 0, query, d_out, Q, 256, 256, dflag);
}